// Round 4
// baseline (621.028 us; speedup 1.0000x reference)
//
#include <hip/hip_runtime.h>

// Problem constants: V=27, E=64, H=128, B=256, S=512 (enc and dec)
#define V_ 27
#define E_ 64
#define H_ 128
#define S_ 512
#define HPAD 192   // h stored as 16 groups of 8 floats, padded to 12-word stride

// Barrier WITHOUT vmcnt drain: LDS visibility only. Global stores stay in flight.
#define BAR() asm volatile("s_waitcnt lgkmcnt(0)\n\ts_barrier" ::: "memory")

template<int CTRL>
__device__ __forceinline__ float dpp_add(float x) {
    int y = __builtin_amdgcn_update_dpp(0, __builtin_bit_cast(int, x), CTRL, 0xF, 0xF, true);
    return x + __builtin_bit_cast(float, y);
}
// Sum across the 16 lanes of a DPP row (kk = lane&15) — VALU-only, no LDS pipe.
__device__ __forceinline__ float rowsum16(float x) {
    x = dpp_add<0x128>(x);  // row_ror:8
    x = dpp_add<0x124>(x);  // row_ror:4
    x = dpp_add<0x122>(x);  // row_ror:2
    x = dpp_add<0x121>(x);  // row_ror:1
    return x;
}

// tanh(z) = 1 - 2/(e^{2z}+1); fp32-stable at both extremes.
__device__ __forceinline__ float fast_tanhf(float z) {
    float e = __expf(2.0f * z);
    return 1.0f - __fdividef(2.0f, e + 1.0f);
}

// Lane mapping: wave w owns j in [16w,16w+16). lane = (jl<<4)|kk:
//   jl = lane>>4 (0..3): owns 4 j's  j0..j0+3, j0 = 16w + 4jl
//   kk = lane&15 (0..15): owns 8 k's [8kk, 8kk+8)
// Each loaded h value feeds 4 recurrence FMAs (+1 dense FMA in decoder).
// Split-k=16 reduced with 4 DPP row_ror adds; kk==0 lanes write h (b128).
// Dense logit v = (w<<2)|jl (32 slots, 27 used) reuses the same hv[8].
template<bool DENSE>
__device__ __forceinline__ void rnn_step(
    const float* __restrict__ hsrc, float* __restrict__ hdst,
    const float* __restrict__ wh,     // [32] Wh[8kk+i][j0+m]
    const float* __restrict__ wd,     // [8]  dense_W[8kk+i][v]
    float db,
    const int* __restrict__ idp,      // &ids[t] (idp[2] = prefetch id_{t+2})
    const float* __restrict__ Tb,     // xw table base for this phase
    int kk, int j0, int wrw, bool kk0,
    int& id_b, float4& Tv,            // software pipeline: id_{t+1}, Tv_t
    bool dostore, float* __restrict__ outp)
{
    int    id_n = idp[2];
    float4 Tv_n = *(const float4*)(Tb + id_b * H_ + j0);   // prefetch Tv_{t+1}
    const float4* hb = (const float4*)(hsrc + 12 * kk);
    float4 ha = hb[0], hc = hb[1];
    float hv[8] = {ha.x, ha.y, ha.z, ha.w, hc.x, hc.y, hc.z, hc.w};
    float p[4] = {0.f, 0.f, 0.f, 0.f};
    #pragma unroll
    for (int m = 0; m < 4; ++m)
        #pragma unroll
        for (int i = 0; i < 8; ++i)
            p[m] = fmaf(hv[i], wh[m * 8 + i], p[m]);
    p[0] = rowsum16(p[0]);
    p[1] = rowsum16(p[1]);
    p[2] = rowsum16(p[2]);
    p[3] = rowsum16(p[3]);
    float4 hn;
    hn.x = fast_tanhf(p[0] + Tv.x);
    hn.y = fast_tanhf(p[1] + Tv.y);
    hn.z = fast_tanhf(p[2] + Tv.z);
    hn.w = fast_tanhf(p[3] + Tv.w);
    if (kk0) *(float4*)(hdst + wrw) = hn;
    if (DENSE) {
        float d = 0.f;
        #pragma unroll
        for (int i = 0; i < 8; ++i) d = fmaf(hv[i], wd[i], d);
        d = rowsum16(d);
        if (dostore) outp[0] = d + db;   // vmcnt never drained by BAR
    }
    BAR();
    id_b = id_n;
    Tv   = Tv_n;
}

__global__ __launch_bounds__(512, 2)
void seq2seq_rnn_kernel(const int* __restrict__ enc_ids, const int* __restrict__ dec_ids,
                        const float* __restrict__ embed,
                        const float* __restrict__ enc_Wx, const float* __restrict__ enc_Wh,
                        const float* __restrict__ enc_b,
                        const float* __restrict__ dec_Wx, const float* __restrict__ dec_Wh,
                        const float* __restrict__ dec_b,
                        const float* __restrict__ dense_W, const float* __restrict__ dense_b,
                        float* __restrict__ out) {
    __shared__ __align__(16) float lds_T[2 * V_ * H_];   // xw tables [tbl][v][j]
    __shared__ __align__(16) float lds_h0[HPAD];
    __shared__ __align__(16) float lds_h1[HPAD];
    __shared__ __align__(16) float lds_emb[V_ * E_];
    __shared__ __align__(16) int   lds_ids[2 * S_ + 2];

    const int tid  = threadIdx.x;
    const int b    = blockIdx.x;
    const int lane = tid & 63;
    const int w    = tid >> 6;
    const int jl   = lane >> 4;
    const int kk   = lane & 15;
    const int j0   = (w << 4) + (jl << 2);           // first of 4 owned j
    const int wrw  = 12 * (j0 >> 3) + (j0 & 7);      // padded write word (16B-aligned)
    const bool kk0 = (kk == 0);
    const int vd   = (w << 2) | jl;                  // dense logit slot (27 of 32 used)

    // ---- stage embed, ids; zero h0 ----
    for (int i = tid; i < V_ * E_; i += 512) lds_emb[i] = embed[i];
    if (tid < 256) ((int2*)lds_ids)[tid] = ((const int2*)(enc_ids + b * S_))[tid];
    else ((int2*)(lds_ids + S_))[tid - 256] = ((const int2*)(dec_ids + b * S_))[tid - 256];
    if (tid < 2) lds_ids[2 * S_ + tid] = 0;
    if (tid < HPAD) lds_h0[tid] = 0.0f;
    __syncthreads();

    // ---- T tables: T[tbl][v][j] = b[j] + sum_e embed[v][e]*Wx[e][j] ----
    for (int idx = tid; idx < 2 * V_ * H_; idx += 512) {
        int tbl = idx / (V_ * H_);
        int rem = idx - tbl * (V_ * H_);
        int v = rem >> 7, j = rem & (H_ - 1);
        const float* Wx = tbl ? dec_Wx : enc_Wx;
        const float* bb = tbl ? dec_b : enc_b;
        float sacc = bb[j];
        #pragma unroll
        for (int e = 0; e < E_; ++e)
            sacc = fmaf(lds_emb[v * E_ + e], Wx[e * H_ + j], sacc);
        lds_T[idx] = sacc;
    }

    // ---- recurrent weights: wh[m*8+i] = Wh[8kk+i][j0+m] (encoder first) ----
    float wh[32];
    #pragma unroll
    for (int m = 0; m < 4; ++m)
        #pragma unroll
        for (int i = 0; i < 8; ++i)
            wh[m * 8 + i] = enc_Wh[(8 * kk + i) * H_ + j0 + m];

    // ---- dense weights: wd[i] = dense_W[8kk+i][vd] ----
    float wd[8]; float db = 0.0f;
    if (vd < V_) {
        db = dense_b[vd];
        #pragma unroll
        for (int i = 0; i < 8; ++i) wd[i] = dense_W[(8 * kk + i) * V_ + vd];
    } else {
        #pragma unroll
        for (int i = 0; i < 8; ++i) wd[i] = 0.0f;
    }
    const bool dlane = kk0 && (vd < V_);
    float* outd = out + b * (S_ * V_) + vd;   // dense store base for this lane
    __syncthreads();  // T tables ready

    // ================= encoder: 512 steps =================
    {
        int    id_b = lds_ids[1];
        float4 Tv   = *(const float4*)(lds_T + lds_ids[0] * H_ + j0);
        for (int t = 0; t < S_; t += 2) {
            rnn_step<false>(lds_h0, lds_h1, wh, wd, db, lds_ids + t,     lds_T,
                            kk, j0, wrw, kk0, id_b, Tv, false, nullptr);
            rnn_step<false>(lds_h1, lds_h0, wh, wd, db, lds_ids + t + 1, lds_T,
                            kk, j0, wrw, kk0, id_b, Tv, false, nullptr);
        }
    }

    // swap to decoder recurrent weights (registers private)
    #pragma unroll
    for (int m = 0; m < 4; ++m)
        #pragma unroll
        for (int i = 0; i < 8; ++i)
            wh[m * 8 + i] = dec_Wh[(8 * kk + i) * H_ + j0 + m];

    // ================= decoder: 512 steps; dense piggybacked on hv =================
    // Step t reads buffer holding dec state after step t-1 -> dense -> out[(t-1)*V].
    {
        const int*   ids_d = lds_ids + S_;
        const float* Td    = lds_T + V_ * H_;
        int    id_b = ids_d[1];
        float4 Tv   = *(const float4*)(Td + ids_d[0] * H_ + j0);
        for (int t = 0; t < S_; t += 2) {
            rnn_step<true>(lds_h0, lds_h1, wh, wd, db, ids_d + t,     Td,
                           kk, j0, wrw, kk0, id_b, Tv, dlane && (t > 0), outd + (t - 1) * V_);
            rnn_step<true>(lds_h1, lds_h0, wh, wd, db, ids_d + t + 1, Td,
                           kk, j0, wrw, kk0, id_b, Tv, dlane, outd + t * V_);
        }
    }

    // epilogue: dense on final state (decoder t=511 wrote lds_h0) -> logits[511]
    {
        const float4* hb = (const float4*)(lds_h0 + 12 * kk);
        float4 ha = hb[0], hc = hb[1];
        float hv[8] = {ha.x, ha.y, ha.z, ha.w, hc.x, hc.y, hc.z, hc.w};
        float d = 0.f;
        #pragma unroll
        for (int i = 0; i < 8; ++i) d = fmaf(hv[i], wd[i], d);
        d = rowsum16(d);
        if (dlane) outd[(S_ - 1) * V_] = d + db;
    }
}

extern "C" void kernel_launch(void* const* d_in, const int* in_sizes, int n_in,
                              void* d_out, int out_size, void* d_ws, size_t ws_size,
                              hipStream_t stream) {
    const int*   enc_ids = (const int*)d_in[0];
    const int*   dec_ids = (const int*)d_in[1];
    const float* embed   = (const float*)d_in[2];
    const float* enc_Wx  = (const float*)d_in[3];
    const float* enc_Wh  = (const float*)d_in[4];
    const float* enc_b   = (const float*)d_in[5];
    const float* dec_Wx  = (const float*)d_in[6];
    const float* dec_Wh  = (const float*)d_in[7];
    const float* dec_b   = (const float*)d_in[8];
    const float* dense_W = (const float*)d_in[9];
    const float* dense_b = (const float*)d_in[10];
    float* out = (float*)d_out;

    hipLaunchKernelGGL(seq2seq_rnn_kernel, dim3(256), dim3(512), 0, stream,
                       enc_ids, dec_ids, embed, enc_Wx, enc_Wh, enc_b,
                       dec_Wx, dec_Wh, dec_b, dense_W, dense_b, out);
}

// Round 6
// 413.994 us; speedup vs baseline: 1.5001x; 1.5001x over previous
//
#include <hip/hip_runtime.h>

// Problem constants: V=27, E=64, H=128, B=256, S=512 (enc and dec)
#define V_ 27
#define E_ 64
#define H_ 128
#define S_ 512

// Barrier WITHOUT vmcnt drain: LDS visibility only. Global loads/stores stay in flight.
#define BAR() asm volatile("s_waitcnt lgkmcnt(0)\n\ts_barrier" ::: "memory")

// Hazard-safe DPP add: compiler-generated v_mov_b32_dpp + v_add_f32 (the
// GCNHazardRecognizer inserts required wait states; raw asm DPP does NOT — R5 bug).
template<int CTRL>
__device__ __forceinline__ float dpp_add(float x) {
    int y = __builtin_amdgcn_update_dpp(0, __builtin_bit_cast(int, x), CTRL, 0xF, 0xF, true);
    return x + __builtin_bit_cast(float, y);
}
#define QP_1032 0xB1   // quad_perm [1,0,3,2]
#define QP_2301 0x4E   // quad_perm [2,3,0,1]
#define RR8 0x128      // row_ror:8
#define RR4 0x124      // row_ror:4
#define RR2 0x122      // row_ror:2
#define RR1 0x121      // row_ror:1

// tanh(z) = 1 - 2/(e^{2z}+1); fp32-stable at both extremes.
__device__ __forceinline__ float fast_tanhf(float z) {
    float e = __expf(2.0f * z);
    return 1.0f - __fdividef(2.0f, e + 1.0f);
}

// ---------- prep kernel: T[tbl][v][j] = b[j] + sum_e embed[v][e]*Wx[e][j] ----------
__global__ void prep_T(const float* __restrict__ embed,
                       const float* __restrict__ eWx, const float* __restrict__ eb,
                       const float* __restrict__ dWx, const float* __restrict__ db_,
                       float* __restrict__ Tg) {
    int tbl = blockIdx.x / V_;
    int v   = blockIdx.x - tbl * V_;
    int j   = threadIdx.x;
    const float* Wx = tbl ? dWx : eWx;
    const float* bb = tbl ? db_ : eb;
    float s = bb[j];
    #pragma unroll
    for (int e = 0; e < E_; ++e) s = fmaf(embed[v * E_ + e], Wx[e * H_ + j], s);
    Tg[tbl * V_ * H_ + v * H_ + j] = s;
}

// ---------- main kernel ----------
// 256 blocks x 512 threads (8 waves). Wave w owns j in [16w,16w+16).
// lane = (jl<<4)|kk: jl=lane>>4 (4-j subgroup), kk=lane&15 (8-k slice).
// Per lane: 2 ds_read_b128 of h, 32 FMA into p0..p3.
// Reduction: quad-reduce each p_m (DPP), diagonal-select m=lane&3 (cndmask with
// loop-invariant masks), row_ror:8/4 stride-4 sum -> ONE tanh per lane for
// jdiag = 16w+4jl+(lane&3). Writers kk<4, b32. Tv from GLOBAL T table,
// prefetched one step ahead (BAR never drains vmcnt). Dense piggybacks on hv.
template<bool DENSE, bool LOADPAIR>
__device__ __forceinline__ void rnn_step(
    const float* __restrict__ hsrc, float* __restrict__ hdst,
    const float* __restrict__ wh,     // [32] Wh[8kk+i][j0+m]
    const float* __restrict__ wd,     // [8]  dense_W[8kk+i][vd]
    float db,
    const int* __restrict__ idp,      // &ids[t] (even t when LOADPAIR)
    const float* __restrict__ Tg,     // global T table base for this phase
    int kk, int jdiag, int wrword, bool wrlane, bool c1, bool c2,
    int& id_next, int2& idpr, float& Tv,   // pipeline state
    bool dostore, float* __restrict__ outp)
{
    int2 idpr_n;
    if (LOADPAIR) idpr_n = *(const int2*)(idp + 2);     // ids[t+2], ids[t+3] (b64)
    float Tv_n = Tg[id_next * H_ + jdiag];              // global prefetch for t+1
    const float4* hb = (const float4*)(hsrc + 12 * kk);
    float4 ha = hb[0], hc = hb[1];
    float hv[8] = {ha.x, ha.y, ha.z, ha.w, hc.x, hc.y, hc.z, hc.w};
    float p0 = 0.f, p1 = 0.f, p2 = 0.f, p3 = 0.f;
    #pragma unroll
    for (int i = 0; i < 8; ++i) {
        p0 = fmaf(hv[i], wh[0 * 8 + i], p0);
        p1 = fmaf(hv[i], wh[1 * 8 + i], p1);
        p2 = fmaf(hv[i], wh[2 * 8 + i], p2);
        p3 = fmaf(hv[i], wh[3 * 8 + i], p3);
    }
    // quad-reduce each component (sum over kk&~3 .. kk|3, i.e. k in [32a,32a+32))
    p0 = dpp_add<QP_2301>(dpp_add<QP_1032>(p0));
    p1 = dpp_add<QP_2301>(dpp_add<QP_1032>(p1));
    p2 = dpp_add<QP_2301>(dpp_add<QP_1032>(p2));
    p3 = dpp_add<QP_2301>(dpp_add<QP_1032>(p3));
    // diagonal select: lane takes component m = lane&3 (masks loop-invariant)
    float s01 = c1 ? p1 : p0;
    float s23 = c1 ? p3 : p2;
    float r   = c2 ? s23 : s01;
    // sum the 4 quad-sums across the row (stride-4 same-phase lanes)
    r = dpp_add<RR8>(r);
    r = dpp_add<RR4>(r);
    float hnew = fast_tanhf(r + Tv);
    if (wrlane) hdst[wrword] = hnew;                    // b32, 16 lanes/wave
    if (DENSE) {
        float d = 0.f;
        #pragma unroll
        for (int i = 0; i < 8; ++i) d = fmaf(hv[i], wd[i], d);
        d = dpp_add<RR1>(dpp_add<RR2>(dpp_add<RR4>(dpp_add<RR8>(d))));
        if (dostore) outp[0] = d + db;                  // vmcnt never drained by BAR
    }
    BAR();
    if (LOADPAIR) { idpr = idpr_n; id_next = idpr_n.x; }
    else          { id_next = idpr.y; }
    Tv = Tv_n;
}

__global__ __launch_bounds__(512, 1)
void seq2seq_rnn_kernel(const int* __restrict__ enc_ids, const int* __restrict__ dec_ids,
                        const float* __restrict__ enc_Wh, const float* __restrict__ dec_Wh,
                        const float* __restrict__ dense_W, const float* __restrict__ dense_b,
                        const float* __restrict__ Tg,      // [2][27][128] in d_ws
                        float* __restrict__ out) {
    __shared__ __align__(16) float lds_h0[192];   // 16 groups of 8, stride 12
    __shared__ __align__(16) float lds_h1[192];
    __shared__ __align__(16) int   lds_ids[2 * S_ + 2];

    const int tid  = threadIdx.x;
    const int b    = blockIdx.x;
    const int lane = tid & 63;
    const int w    = tid >> 6;
    const int jl   = lane >> 4;
    const int kk   = lane & 15;
    const int j0     = (w << 4) + (jl << 2);
    const int jdiag  = j0 + (lane & 3);
    const int wrword = 12 * (jdiag >> 3) + (jdiag & 7);
    const bool wrlane = (kk < 4);
    const bool c1 = (lane & 1) != 0;
    const bool c2 = (lane & 2) != 0;
    const int vd   = (w << 2) | jl;               // dense logit slot (27 of 32 used)

    // ---- stage ids; zero h0 ----
    if (tid < 256) ((int2*)lds_ids)[tid] = ((const int2*)(enc_ids + b * S_))[tid];
    else ((int2*)(lds_ids + S_))[tid - 256] = ((const int2*)(dec_ids + b * S_))[tid - 256];
    if (tid < 2) lds_ids[2 * S_ + tid] = 0;
    if (tid < 192) lds_h0[tid] = 0.0f;

    // ---- recurrent weights: wh[m*8+i] = Wh[8kk+i][j0+m] (encoder first) ----
    float wh[32];
    #pragma unroll
    for (int m = 0; m < 4; ++m)
        #pragma unroll
        for (int i = 0; i < 8; ++i)
            wh[m * 8 + i] = enc_Wh[(8 * kk + i) * H_ + j0 + m];

    // ---- dense weights: wd[i] = dense_W[8kk+i][vd] ----
    float wd[8]; float db = 0.0f;
    if (vd < V_) {
        db = dense_b[vd];
        #pragma unroll
        for (int i = 0; i < 8; ++i) wd[i] = dense_W[(8 * kk + i) * V_ + vd];
    } else {
        #pragma unroll
        for (int i = 0; i < 8; ++i) wd[i] = 0.0f;
    }
    const bool dlane = (kk == 0) && (vd < V_);
    float* outd = out + b * (S_ * V_) + vd;
    __syncthreads();   // ids + h0 ready

    // ================= encoder: 512 steps =================
    {
        int2  idpr;
        int   id_next = lds_ids[1];
        float Tv      = Tg[lds_ids[0] * H_ + jdiag];
        for (int t = 0; t < S_; t += 2) {
            rnn_step<false, true >(lds_h0, lds_h1, wh, wd, db, lds_ids + t, Tg,
                                   kk, jdiag, wrword, wrlane, c1, c2,
                                   id_next, idpr, Tv, false, nullptr);
            rnn_step<false, false>(lds_h1, lds_h0, wh, wd, db, lds_ids + t, Tg,
                                   kk, jdiag, wrword, wrlane, c1, c2,
                                   id_next, idpr, Tv, false, nullptr);
        }
    }

    // swap to decoder recurrent weights (registers private)
    #pragma unroll
    for (int m = 0; m < 4; ++m)
        #pragma unroll
        for (int i = 0; i < 8; ++i)
            wh[m * 8 + i] = dec_Wh[(8 * kk + i) * H_ + j0 + m];

    // ================= decoder: 512 steps; dense piggybacked =================
    // Step t reads buffer holding dec state after step t-1 -> dense -> out[(t-1)*V].
    {
        const int*   ids_d = lds_ids + S_;
        const float* Td    = Tg + V_ * H_;
        int2  idpr;
        int   id_next = ids_d[1];
        float Tv      = Td[ids_d[0] * H_ + jdiag];
        for (int t = 0; t < S_; t += 2) {
            rnn_step<true, true >(lds_h0, lds_h1, wh, wd, db, ids_d + t, Td,
                                  kk, jdiag, wrword, wrlane, c1, c2,
                                  id_next, idpr, Tv,
                                  dlane && (t > 0), outd + (t - 1) * V_);
            rnn_step<true, false>(lds_h1, lds_h0, wh, wd, db, ids_d + t, Td,
                                  kk, jdiag, wrword, wrlane, c1, c2,
                                  id_next, idpr, Tv,
                                  dlane, outd + t * V_);
        }
    }

    // epilogue: dense on final state (decoder t=511 wrote lds_h0) -> logits[511]
    {
        const float4* hb = (const float4*)(lds_h0 + 12 * kk);
        float4 ha = hb[0], hc = hb[1];
        float hv[8] = {ha.x, ha.y, ha.z, ha.w, hc.x, hc.y, hc.z, hc.w};
        float d = 0.f;
        #pragma unroll
        for (int i = 0; i < 8; ++i) d = fmaf(hv[i], wd[i], d);
        d = dpp_add<RR1>(dpp_add<RR2>(dpp_add<RR4>(dpp_add<RR8>(d))));
        if (dlane) outd[(S_ - 1) * V_] = d + db;
    }
}

extern "C" void kernel_launch(void* const* d_in, const int* in_sizes, int n_in,
                              void* d_out, int out_size, void* d_ws, size_t ws_size,
                              hipStream_t stream) {
    const int*   enc_ids = (const int*)d_in[0];
    const int*   dec_ids = (const int*)d_in[1];
    const float* embed   = (const float*)d_in[2];
    const float* enc_Wx  = (const float*)d_in[3];
    const float* enc_Wh  = (const float*)d_in[4];
    const float* enc_b   = (const float*)d_in[5];
    const float* dec_Wx  = (const float*)d_in[6];
    const float* dec_Wh  = (const float*)d_in[7];
    const float* dec_b   = (const float*)d_in[8];
    const float* dense_W = (const float*)d_in[9];
    const float* dense_b = (const float*)d_in[10];
    float* out = (float*)d_out;
    float* Tg  = (float*)d_ws;   // 2*27*128 floats = 27648 B

    hipLaunchKernelGGL(prep_T, dim3(2 * V_), dim3(H_), 0, stream,
                       embed, enc_Wx, enc_b, dec_Wx, dec_b, Tg);
    hipLaunchKernelGGL(seq2seq_rnn_kernel, dim3(256), dim3(512), 0, stream,
                       enc_ids, dec_ids, enc_Wh, dec_Wh, dense_W, dense_b, Tg, out);
}